// Round 17
// baseline (332.296 us; speedup 1.0000x reference)
//
#include <hip/hip_runtime.h>
#include <hip/hip_bf16.h>
#include <math.h>

#define NS 4096      // samples
#define NC 512       // clusters
#define ND 64        // feature dim
#define NK 10        // classes
#define NPAIR 2080   // upper-triangle pairs (e<=d) of 64x64
#define KP 2176      // 2080 + 64 (linear) + 1 (const) + 31 zero-pad; 68*32
#define BOFF 2080
#define KOFF 2144
#define KSPLIT 4
#define KT_PER (KP / 32 / KSPLIT)   // 17 k-chunks per split block
#define ZB 1024                     // d2-zeroing blocks

typedef __attribute__((ext_vector_type(8))) short short8;
typedef __attribute__((ext_vector_type(4))) float floatx4;

__device__ inline unsigned short f2b(float x) {
    __hip_bfloat16 h = __float2bfloat16(x);           // RNE
    return __builtin_bit_cast(unsigned short, h);
}
__device__ inline float b2f(unsigned short u) {
    __hip_bfloat16 h = __builtin_bit_cast(__hip_bfloat16, u);
    return __bfloat162float(h);
}

// true v_readlane_b32 (lane literal at every use site)
__device__ inline float rlane(float v, int k) {
    return __builtin_bit_cast(float, __builtin_amdgcn_readlane(__builtin_bit_cast(int, v), k));
}

// async global->LDS, 16B per lane (m97 lever); dst = wave-uniform base + lane*16
__device__ inline void gl16(const void* g, void* l) {
    __builtin_amdgcn_global_load_lds(
        (const __attribute__((address_space(1))) unsigned int*)g,
        (__attribute__((address_space(3))) unsigned int*)l, 16, 0, 0);
}

// ---------------- (e,d) table with sentinels: val[p] = z[e]*z[d] ------------
__global__ void table_kernel(int2* __restrict__ edt) {
    const int e = threadIdx.x;                        // 64 threads
    int off = e * 64 - (e * (e - 1)) / 2;             // row e starts here
    for (int d = e; d < 64; ++d) edt[off + d - e] = make_int2(e, d);
    edt[BOFF + e] = make_int2(e, 64);                 // linear terms: z*1
    if (e == 0) edt[KOFF] = make_int2(64, 64);        // const term: 1
    if (e < KP - KOFF - 1) edt[KOFF + 1 + e] = make_int2(65, 65);   // pad: 0
}

#define FOR16(M) M(0) M(1) M(2) M(3) M(4) M(5) M(6) M(7) \
                 M(8) M(9) M(10) M(11) M(12) M(13) M(14) M(15)
#define FOR16K(M, K) M(0,K) M(1,K) M(2,K) M(3,K) M(4,K) M(5,K) M(6,K) M(7,K) \
                     M(8,K) M(9,K) M(10,K) M(11,K) M(12,K) M(13,K) M(14,K) M(15,K)

// ---------------- prep (Sigma^-1 + beta pack) + d2 zeroing ------------------
// R15 version VERBATIM (61us, best known). R16's 64-output asm blob spilled
// SGPRs (only ~102 allocatable vs 64 simultaneously-live outputs) -> 175us.
// Fully unrolled k: rp = M[k][j] is a named register; pivot via literal-lane
// v_readlane; (i==k) fixup folds at compile time.
__global__ __launch_bounds__(256, 1) void prep_kernel(
    const float* __restrict__ S, const float* __restrict__ n,
    const float* __restrict__ mu, const int* __restrict__ clab,
    const int2* __restrict__ edt, unsigned short* __restrict__ Bph,
    unsigned short* __restrict__ Bpl, float* __restrict__ d2,
    float* __restrict__ labf)
{
    __shared__ float smem[ND * (ND + 1) + ND];
    float* __restrict__ AcolS = smem;                 // [64][65] Sinv mirror
    float* __restrict__ cbuf  = smem + ND * (ND + 1); // bvec staging

    if (blockIdx.x >= NC) {                           // ---- d2 zero role ----
        const size_t base = (size_t)(blockIdx.x - NC) * 2048 + threadIdx.x * 8;
        *(float4*)&d2[base]     = make_float4(0.f, 0.f, 0.f, 0.f);
        *(float4*)&d2[base + 4] = make_float4(0.f, 0.f, 0.f, 0.f);
        return;
    }

    if (threadIdx.x >= 64) return;                    // prep: wave 0 only
    const int c = blockIdx.x;
    const int j = threadIdx.x;                        // column owned by this lane

    const float inv_nc = 1.0f / n[c];
    const float* __restrict__ Sc = S + (size_t)c * ND * ND + j;

#define DECL(t) float4 A##t;
    FOR16(DECL)
#undef DECL

#define LOADT(t) {                                                   \
    const float x0 = Sc[(4*t+0)*ND] * inv_nc;                        \
    const float x1 = Sc[(4*t+1)*ND] * inv_nc;                        \
    const float x2 = Sc[(4*t+2)*ND] * inv_nc;                        \
    const float x3 = Sc[(4*t+3)*ND] * inv_nc;                        \
    A##t.x = (4*t+0 == j) ? x0 + 1e-6f : x0;                         \
    A##t.y = (4*t+1 == j) ? x1 + 1e-6f : x1;                         \
    A##t.z = (4*t+2 == j) ? x2 + 1e-6f : x2;                         \
    A##t.w = (4*t+3 == j) ? x3 + 1e-6f : x3; }
    FOR16(LOADT)
#undef LOADT

    // ---- 64 fully-unrolled GJ steps (k literal) ----
#define UPDR(u, K) {                                                  \
    const float c0 = rlane(A##u.x, K);                                \
    const float c1 = rlane(A##u.y, K);                                \
    const float c2 = rlane(A##u.z, K);                                \
    const float c3 = rlane(A##u.w, K);                                \
    A##u.x = (4*(u)+0 == (K)) ? rowk : A##u.x * am - c0 * rowk;       \
    A##u.y = (4*(u)+1 == (K)) ? rowk : A##u.y * am - c1 * rowk;       \
    A##u.z = (4*(u)+2 == (K)) ? rowk : A##u.z * am - c2 * rowk;       \
    A##u.w = (4*(u)+3 == (K)) ? rowk : A##u.w * am - c3 * rowk;       \
}
#define STEPC(T, C, K) {                                              \
    const float rp = A##T.C;          /* M[k][j]: own register */     \
    const float pv = rlane(rp, K);    /* pivot M[k][k] */             \
    const float ip = 1.0f / pv;                                       \
    const float rowk = (j == (K)) ? ip : rp * ip;                     \
    const float am   = (j == (K)) ? 0.0f : 1.0f;                      \
    FOR16K(UPDR, K)                                                   \
}
#define STEP4(T) STEPC(T, x, 4*T+0) STEPC(T, y, 4*T+1) \
                 STEPC(T, z, 4*T+2) STEPC(T, w, 4*T+3)
    FOR16(STEP4)
#undef STEP4
#undef STEPC
#undef UPDR

    // mirror Sinv into LDS for the pack gather; fuse y = Sinv*mu
    float y = 0.f;
#define MIR(t) {                                                     \
    *(float4*)&AcolS[j * (ND + 1) + 4*t] = A##t;                     \
    y += A##t.x * mu[c*ND + 4*t]     + A##t.y * mu[c*ND + 4*t + 1]   \
       + A##t.z * mu[c*ND + 4*t + 2] + A##t.w * mu[c*ND + 4*t + 3]; }
    FOR16(MIR)
#undef MIR
    cbuf[j] = -2.0f * y;                              // bvec values
    float kk = mu[c * ND + j] * y;
    #pragma unroll
    for (int off = 32; off > 0; off >>= 1) kk += __shfl_down(kk, off);
    const float kks = __shfl(kk, 0);
    if (j == 0) {
        int lab = 0;
        for (int q = 0; q < NK; ++q) if (clab[c * NK + q] != 0) lab = q;
        labf[c] = (float)lab;
    }
    __builtin_amdgcn_wave_barrier();

    unsigned short* __restrict__ ph = Bph + (size_t)c * KP;
    unsigned short* __restrict__ pl = Bpl + (size_t)c * KP;
    #pragma unroll
    for (int t = 0; t < KP / 64; ++t) {               // 34 iters, p = t*64+j
        const int p = t * 64 + j;
        float val;
        if (p < NPAIR) {
            const int2 ed = edt[p];
            val = (ed.x == ed.y) ? AcolS[ed.x * (ND + 1) + ed.x]
                : (AcolS[ed.y * (ND + 1) + ed.x] + AcolS[ed.x * (ND + 1) + ed.y]);
        } else if (p < KOFF) val = cbuf[p - BOFF];
        else if (p == KOFF)  val = kks;
        else                 val = 0.f;
        const unsigned short h = f2b(val);
        const unsigned short l = f2b(val - b2f(h));
        ph[p] = h;
        pl[p] = l;
    }
}

// ---------------- d2 = Q·Beta^T; A-frags in REGISTERS; 64x256, split-K x4 ----
// R17: each thread computes its OWN MFMA A-fragments (rows i*16+rlo, cols
// quad*8+j) straight from the z-tile -- same ops as before (bit-identical).
// Kills the A-LDS arrays and removes A from the barrier dependency: barriers
// only guard B staging. A-build VALU overlaps the B gl16 flight + other
// blocks' MFMA (m114). R16 showed gemm is barrier-drain-bound (~2100cyc/step
// vs ~500 work) -- this cuts per-step serial work and adds co-residency
// (LDS 49KB -> 3 blocks/CU).
__global__ __launch_bounds__(256, 3) void gemm_kernel(
    const float* __restrict__ data, const int2* __restrict__ edt,
    const unsigned short* __restrict__ Bph, const unsigned short* __restrict__ Bpl,
    float* __restrict__ d2)
{
    __shared__ float zS[64 * 68];                             // z-tile + sentinels
    __shared__ unsigned short BhS[256 * 32], BlS[256 * 32];   // 16KB each

    const int tid  = threadIdx.x;
    const int lane = tid & 63, w = tid >> 6;
    const int quad = lane >> 4, rlo = lane & 15;
    const int m0 = blockIdx.x * 64;      // sample tile
    const int n0 = blockIdx.y * 256;     // cluster tile
    const int koff0 = blockIdx.z * KT_PER * 32;   // this block's K-slice start

    #pragma unroll
    for (int q = 0; q < 4; ++q) {
        const int f = q * 256 + tid;                  // float4 id
        const int r = f >> 4, c4 = f & 15;
        const float4 v = *(const float4*)&data[(size_t)(m0 + r) * ND + c4 * 4];
        *(float4*)&zS[r * 68 + c4 * 4] = v;
    }
    if (tid < 64) { zS[tid * 68 + 64] = 1.0f; zS[tid * 68 + 65] = 0.0f; }

    const int brow = tid >> 2, bseg = tid & 3;
    const unsigned short* bGh[4];
    const unsigned short* bGl[4];
    unsigned short* bLh[4];
    unsigned short* bLl[4];
    #pragma unroll
    for (int rd = 0; rd < 4; ++rd) {
        const size_t off = (size_t)(n0 + rd * 64 + brow) * KP + bseg * 8 + koff0;
        bGh[rd] = Bph + off;
        bGl[rd] = Bpl + off;
        bLh[rd] = BhS + (rd * 256 + tid) * 8;         // lane*16B contiguous
        bLl[rd] = BlS + (rd * 256 + tid) * 8;
    }

    floatx4 acc[4][4] = {};
    __syncthreads();                                  // z-tile visible

    for (int kt = 0; kt < KT_PER; ++kt) {
        const int ko = kt * 32;
        if (kt) __syncthreads();                      // B frags consumed
        #pragma unroll
        for (int rd = 0; rd < 4; ++rd) {
            gl16(bGh[rd] + ko, bLh[rd]);
            gl16(bGl[rd] + ko, bLl[rd]);
        }

        // A-frags in registers, computed while B loads are in flight.
        // Cols quad*8+jj of this k-chunk; rows i*16+rlo.
        int2 ed[8];
        #pragma unroll
        for (int jj = 0; jj < 8; ++jj) ed[jj] = edt[koff0 + ko + quad * 8 + jj];
        short8 ah[4], al[4];
        #pragma unroll
        for (int i = 0; i < 4; ++i) {
            const float* zr = &zS[(i * 16 + rlo) * 68];
            #pragma unroll
            for (int jj = 0; jj < 8; ++jj) {
                const float v = zr[ed[jj].x] * zr[ed[jj].y];
                const unsigned short h = f2b(v);
                const unsigned short l = f2b(v - b2f(h));
                ah[i][jj] = (short)h;
                al[i][jj] = (short)l;
            }
        }
        __syncthreads();                              // B staging visible

        short8 bh[4], bl[4];
        #pragma unroll
        for (int j2 = 0; j2 < 4; ++j2) {
            const int r = w * 64 + j2 * 16 + rlo;
            bh[j2] = *(const short8*)&BhS[r * 32 + quad * 8];
            bl[j2] = *(const short8*)&BlS[r * 32 + quad * 8];
        }
        #pragma unroll
        for (int i = 0; i < 4; ++i)
            #pragma unroll
            for (int j2 = 0; j2 < 4; ++j2) {
                acc[i][j2] = __builtin_amdgcn_mfma_f32_16x16x32_bf16(al[i], bh[j2], acc[i][j2], 0, 0, 0);
                acc[i][j2] = __builtin_amdgcn_mfma_f32_16x16x32_bf16(ah[i], bl[j2], acc[i][j2], 0, 0, 0);
                acc[i][j2] = __builtin_amdgcn_mfma_f32_16x16x32_bf16(ah[i], bh[j2], acc[i][j2], 0, 0, 0);
            }
    }

    // C layout (verified m89): col = lane&15, row = (lane>>4)*4 + reg
    #pragma unroll
    for (int i = 0; i < 4; ++i)
        #pragma unroll
        for (int j2 = 0; j2 < 4; ++j2) {
            const int m = m0 + i * 16 + quad * 4;
            const int nn = n0 + w * 64 + j2 * 16 + rlo;
            #pragma unroll
            for (int r = 0; r < 4; ++r)
                atomicAdd(&d2[(size_t)(m + r) * NC + nn], acc[i][j2][r]);
        }
}

// ---------------- scores / argmaxes: 4 waves/block, one sample per wave -----
__global__ __launch_bounds__(256) void score_kernel(
    const float* __restrict__ d2, const float* __restrict__ labf,
    float* __restrict__ out)
{
    const int s = blockIdx.x * 4 + (threadIdx.x >> 6);
    const int l = threadIdx.x & 63;

    float numer[NK];
    #pragma unroll
    for (int q = 0; q < NK; ++q) numer[q] = 0.f;
    float denom = 0.f, gmax = -1.f;
    int gidx = 0;

    #pragma unroll
    for (int i = 0; i < NC / 256; ++i) {         // float4 per lane, index-ascending
        const int c0 = i * 256 + l * 4;
        const float4 v = *(const float4*)&d2[(size_t)s * NC + c0];
        #pragma unroll
        for (int r = 0; r < 4; ++r) {
            const int c = c0 + r;
            const float G = __expf(-0.5f * ((const float*)&v)[r]);
            denom += G;
            const int lab = (int)labf[c];
            #pragma unroll
            for (int q = 0; q < NK; ++q) numer[q] += (q == lab) ? G : 0.f;
            if (G > gmax) { gmax = G; gidx = c; }   // strict > keeps first index
        }
    }

    #pragma unroll
    for (int off = 32; off > 0; off >>= 1) {
        const float og = __shfl_down(gmax, off);
        const int   oi = __shfl_down(gidx, off);
        if (og > gmax || (og == gmax && oi < gidx)) { gmax = og; gidx = oi; }
        denom += __shfl_down(denom, off);
        #pragma unroll
        for (int q = 0; q < NK; ++q) numer[q] += __shfl_down(numer[q], off);
    }

    if (l == 0) {
        const float inv = 1.0f / (denom + 1e-12f);
        float best = -1.f; int pk = 0;
        #pragma unroll
        for (int q = 0; q < NK; ++q) {
            const float sc = numer[q] * inv;
            out[(size_t)s * NK + q] = sc;
            if (sc > best) { best = sc; pk = q; }
        }
        out[(size_t)NS * NK + s]      = (float)pk;    // pred
        out[(size_t)NS * NK + NS + s] = (float)gidx;  // clusters
    }
}

extern "C" void kernel_launch(void* const* d_in, const int* in_sizes, int n_in,
                              void* d_out, int out_size, void* d_ws, size_t ws_size,
                              hipStream_t stream)
{
    const float* data = (const float*)d_in[0];
    const float* n    = (const float*)d_in[2];
    const float* mu   = (const float*)d_in[3];
    const float* S    = (const float*)d_in[4];
    const int*   clab = (const int*)d_in[5];

    char* w = (char*)d_ws;
    int2* edt = (int2*)(w);                                     //     17,408 B
    unsigned short* Bph = (unsigned short*)(w + 35651584);      //  2,228,224 B
    unsigned short* Bpl = (unsigned short*)(w + 37879808);      //  2,228,224 B
    float* d2   = (float*)(w + 40108032);                       //  8,388,608 B
    float* labf = (float*)(w + 48496640);                       //      2,048 B

    hipLaunchKernelGGL(table_kernel, dim3(1), dim3(64), 0, stream, edt);
    hipLaunchKernelGGL(prep_kernel,  dim3(NC + ZB), dim3(256), 0, stream,
                       S, n, mu, clab, edt, Bph, Bpl, d2, labf);
    hipLaunchKernelGGL(gemm_kernel,  dim3(NS / 64, NC / 256, KSPLIT), dim3(256), 0, stream,
                       data, edt, Bph, Bpl, d2);
    hipLaunchKernelGGL(score_kernel, dim3(NS / 4), dim3(256), 0, stream,
                       d2, labf, (float*)d_out);
}